// Round 13
// baseline (212.594 us; speedup 1.0000x reference)
//
#include <hip/hip_runtime.h>
#include <hip/hip_fp16.h>
#include <math.h>

#define BN 1024      // batch
#define DIN 3072
#define DE 256
#define NK 6
#define KS 8         // critic split-K factor (512 blocks -> 2/CU)
#define GBLKH 1536   // sinkhorn half-step blocks (6/CU)
#define RPBH 4       // rows per half-step block
#define GBLKW 384    // wsum blocks
#define RPBW 16      // rows per wsum block
#define MAXIT 20
#define BM 128       // critic block tile rows
#define BNC 128
#define KSTEP 64     // doubled: 96 MFMAs per barrier pair
#define LDA 68       // LDS row stride (bf16): 136 B -> rows on distinct banks

constexpr float K2F = 14.4269504088896340736f;  // (1/eps)*log2(e), eps=0.1

typedef short short8 __attribute__((ext_vector_type(8)));
typedef float float4v __attribute__((ext_vector_type(4)));
typedef unsigned short ushort4v __attribute__((ext_vector_type(4)));

__device__ __forceinline__ unsigned short f2bf(float x) {  // RNE, no NaN path
  union { float f; unsigned u; } v; v.f = x;
  unsigned r = v.u + 0x7FFF + ((v.u >> 16) & 1);
  return (unsigned short)(r >> 16);
}
__device__ __forceinline__ float bf2f(unsigned short h) {
  union { float f; unsigned u; } v; v.u = ((unsigned)h) << 16;
  return v.f;
}

// ---------------- Wc -> WcT (256x3072) split into bf16 hi/lo ----------------
__global__ __launch_bounds__(256) void wct_prep(
    const float* __restrict__ Wc, unsigned short* __restrict__ WcTh,
    unsigned short* __restrict__ WcTl) {
  __shared__ float tile[64][65];
  const int t = threadIdx.x;
  const int kb = blockIdx.x * 64, cb = blockIdx.y * 64;
#pragma unroll
  for (int i = 0; i < 4; ++i) {
    int k = (t >> 4) + i * 16;
    int c = (t & 15) * 4;
    float4 v = *(const float4*)&Wc[(size_t)(kb + k) * DE + cb + c];
    tile[k][c] = v.x; tile[k][c + 1] = v.y; tile[k][c + 2] = v.z; tile[k][c + 3] = v.w;
  }
  __syncthreads();
#pragma unroll
  for (int i = 0; i < 4; ++i) {
    int c = (t >> 4) + i * 16;
    int k = (t & 15) * 4;
    ushort4v h, l;
#pragma unroll
    for (int j = 0; j < 4; ++j) {
      float v = tile[k + j][c];
      unsigned short hh = f2bf(v);
      h[j] = hh; l[j] = f2bf(v - bf2f(hh));
    }
    *(ushort4v*)&WcTh[(size_t)(cb + c) * DIN + kb + k] = h;
    *(ushort4v*)&WcTl[(size_t)(cb + c) * DIN + kb + k] = l;
  }
}

// ------ critic GEMM via bf16x2-split MFMA, KSTEP=64 (6 barrier pairs) -------
__global__ __launch_bounds__(256) void critic_mfma(
    const float* __restrict__ x, const float* __restrict__ xp,
    const float* __restrict__ y, const float* __restrict__ yp,
    const unsigned short* __restrict__ WcTh,
    const unsigned short* __restrict__ WcTl, float* __restrict__ Pp) {
  __shared__ unsigned short Ah[BM][LDA], Al[BM][LDA];
  __shared__ unsigned short Bh[BNC][LDA], Bl[BNC][LDA];
  const int t = threadIdx.x;
  const int rt = blockIdx.x, ct = blockIdx.y, ks = blockIdx.z;
  const int R0 = rt * BM;
  const int m = R0 >> 10, r0 = R0 & 1023;
  const float* src = (m == 0) ? x : (m == 1) ? xp : (m == 2) ? y : yp;
  const int wid = t >> 6, lane = t & 63;
  const int wy = wid >> 1, wx = wid & 1;
  const int fr = lane & 15, fg = lane >> 4;

  float4v acc[4][4];
#pragma unroll
  for (int i = 0; i < 4; ++i)
#pragma unroll
    for (int j = 0; j < 4; ++j) acc[i][j] = (float4v){0.f, 0.f, 0.f, 0.f};

  const int kbase = ks * (DIN / KS);
  const int arow = t >> 1, akq = (t & 1) * 32;   // 128 rows x 64 k, 32/thread

  for (int k0 = 0; k0 < DIN / KS; k0 += KSTEP) {
    const int kg = kbase + k0;
    __syncthreads();
    {  // stage A: f32 -> bf16 hi/lo
      const float* ap = src + (size_t)(r0 + arow) * DIN + kg + akq;
      float av[32];
#pragma unroll
      for (int q = 0; q < 8; ++q) {
        float4 v = *(const float4*)(ap + 4 * q);
        av[4 * q] = v.x; av[4 * q + 1] = v.y; av[4 * q + 2] = v.z; av[4 * q + 3] = v.w;
      }
#pragma unroll
      for (int g = 0; g < 4; ++g) {
        short8 h, l;
#pragma unroll
        for (int j = 0; j < 8; ++j) {
          unsigned short hh = f2bf(av[8 * g + j]);
          h[j] = (short)hh; l[j] = (short)f2bf(av[8 * g + j] - bf2f(hh));
        }
        *(short8*)&Ah[arow][akq + 8 * g] = h;
        *(short8*)&Al[arow][akq + 8 * g] = l;
      }
    }
    {  // stage B: already bf16 hi/lo
      const unsigned short* bph = WcTh + (size_t)(ct * BNC + arow) * DIN + kg + akq;
      const unsigned short* bpl = WcTl + (size_t)(ct * BNC + arow) * DIN + kg + akq;
#pragma unroll
      for (int g = 0; g < 4; ++g) {
        *(short8*)&Bh[arow][akq + 8 * g] = *(const short8*)(bph + 8 * g);
        *(short8*)&Bl[arow][akq + 8 * g] = *(const short8*)(bpl + 8 * g);
      }
    }
    __syncthreads();
#pragma unroll
    for (int kk = 0; kk < KSTEP; kk += 32) {
      short8 afh[4], afl[4], bfh[4], bfl[4];
#pragma unroll
      for (int i = 0; i < 4; ++i) {
        int row = wy * 64 + i * 16 + fr;
        afh[i] = *(const short8*)&Ah[row][kk + fg * 8];
        afl[i] = *(const short8*)&Al[row][kk + fg * 8];
        int col = wx * 64 + i * 16 + fr;
        bfh[i] = *(const short8*)&Bh[col][kk + fg * 8];
        bfl[i] = *(const short8*)&Bl[col][kk + fg * 8];
      }
#pragma unroll
      for (int i = 0; i < 4; ++i)
#pragma unroll
        for (int j = 0; j < 4; ++j) {
          acc[i][j] = __builtin_amdgcn_mfma_f32_16x16x32_bf16(afh[i], bfh[j], acc[i][j], 0, 0, 0);
          acc[i][j] = __builtin_amdgcn_mfma_f32_16x16x32_bf16(afh[i], bfl[j], acc[i][j], 0, 0, 0);
          acc[i][j] = __builtin_amdgcn_mfma_f32_16x16x32_bf16(afl[i], bfh[j], acc[i][j], 0, 0, 0);
        }
    }
  }
#pragma unroll
  for (int i = 0; i < 4; ++i)
#pragma unroll
    for (int j = 0; j < 4; ++j) {
      int grow = R0 + wy * 64 + i * 16 + fg * 4;
      int gcol = ct * BNC + wx * 64 + j * 16 + fr;
#pragma unroll
      for (int reg = 0; reg < 4; ++reg)
        Pp[((size_t)ks * 4096 + grow + reg) * DE + gcol] = acc[i][j][reg];
    }
}

// -------- combine split-K + bias + row-normalize -> F as bf16 hi/lo ---------
__global__ __launch_bounds__(256) void critic_norm(
    const float* __restrict__ Pp, const float* __restrict__ bc,
    unsigned short* __restrict__ Fh, unsigned short* __restrict__ Fl) {
  __shared__ double red[4];
  __shared__ double nrm2s;
  const int row = blockIdx.x, t = threadIdx.x;
  double val = (double)bc[t];
#pragma unroll
  for (int ks = 0; ks < KS; ++ks)
    val += (double)Pp[((size_t)ks * 4096 + row) * DE + t];
  double ss = val * val;
#pragma unroll
  for (int off = 32; off; off >>= 1) ss += __shfl_down(ss, off);
  if ((t & 63) == 0) red[t >> 6] = ss;
  __syncthreads();
  if (t == 0) nrm2s = red[0] + red[1] + red[2] + red[3];
  __syncthreads();
  float fv = (float)(val / sqrt(nrm2s));
  unsigned short h = f2bf(fv);
  Fh[(size_t)row * DE + t] = h;
  Fl[(size_t)row * DE + t] = f2bf(fv - bf2f(h));
}

// ---- 6 cosine matrices via MFMA, KSTEP=64 -> Eh fp16 + EhT -----------------
__global__ __launch_bounds__(256) void cosine_mfma(
    const unsigned short* __restrict__ Fh, const unsigned short* __restrict__ Fl,
    __half* __restrict__ E, __half* __restrict__ ET) {
  __shared__ unsigned short Ah[128][LDA], Al[128][LDA];
  __shared__ unsigned short Bh[128][LDA], Bl[128][LDA];
  const int pa[NK] = {0, 0, 1, 1, 0, 2};
  const int pb[NK] = {2, 3, 2, 3, 1, 3};
  const int p = blockIdx.z;
  const int ti = blockIdx.y, tj = blockIdx.x;
  const int t = threadIdx.x;
  const int wid = t >> 6, lane = t & 63;
  const int wy = wid >> 1, wx = wid & 1;
  const int fr = lane & 15, fg = lane >> 4;
  const int arow = t >> 1, akq = (t & 1) * 32;
  const unsigned short* ahp = Fh + (size_t)(pa[p] * BN + ti * 128 + arow) * DE + akq;
  const unsigned short* alp = Fl + (size_t)(pa[p] * BN + ti * 128 + arow) * DE + akq;
  const unsigned short* bhp = Fh + (size_t)(pb[p] * BN + tj * 128 + arow) * DE + akq;
  const unsigned short* blp = Fl + (size_t)(pb[p] * BN + tj * 128 + arow) * DE + akq;

  float4v acc[4][4];
#pragma unroll
  for (int i = 0; i < 4; ++i)
#pragma unroll
    for (int j = 0; j < 4; ++j) acc[i][j] = (float4v){0.f, 0.f, 0.f, 0.f};

  for (int kg = 0; kg < DE; kg += KSTEP) {
    __syncthreads();
#pragma unroll
    for (int g = 0; g < 4; ++g) {
      *(short8*)&Ah[arow][akq + 8 * g] = *(const short8*)(ahp + kg + 8 * g);
      *(short8*)&Al[arow][akq + 8 * g] = *(const short8*)(alp + kg + 8 * g);
      *(short8*)&Bh[arow][akq + 8 * g] = *(const short8*)(bhp + kg + 8 * g);
      *(short8*)&Bl[arow][akq + 8 * g] = *(const short8*)(blp + kg + 8 * g);
    }
    __syncthreads();
#pragma unroll
    for (int kk = 0; kk < KSTEP; kk += 32) {
      short8 afh[4], afl[4], bfh[4], bfl[4];
#pragma unroll
      for (int i = 0; i < 4; ++i) {
        int row = wy * 64 + i * 16 + fr;
        afh[i] = *(const short8*)&Ah[row][kk + fg * 8];
        afl[i] = *(const short8*)&Al[row][kk + fg * 8];
        int col = wx * 64 + i * 16 + fr;
        bfh[i] = *(const short8*)&Bh[col][kk + fg * 8];
        bfl[i] = *(const short8*)&Bl[col][kk + fg * 8];
      }
#pragma unroll
      for (int i = 0; i < 4; ++i)
#pragma unroll
        for (int j = 0; j < 4; ++j) {
          acc[i][j] = __builtin_amdgcn_mfma_f32_16x16x32_bf16(afh[i], bfh[j], acc[i][j], 0, 0, 0);
          acc[i][j] = __builtin_amdgcn_mfma_f32_16x16x32_bf16(afh[i], bfl[j], acc[i][j], 0, 0, 0);
          acc[i][j] = __builtin_amdgcn_mfma_f32_16x16x32_bf16(afl[i], bfh[j], acc[i][j], 0, 0, 0);
        }
    }
  }
#pragma unroll
  for (int i = 0; i < 4; ++i)
#pragma unroll
    for (int j = 0; j < 4; ++j) {
      int grow0 = ti * 128 + wy * 64 + i * 16 + fg * 4;
      int gcol = tj * 128 + wx * 64 + j * 16 + fr;
      union { __half h[4]; uint2 w; } pk;
#pragma unroll
      for (int reg = 0; reg < 4; ++reg)
        pk.h[reg] = __float2half(exp2f(acc[i][j][reg] * K2F));
      __half* ep = E + ((size_t)p << 20) + (size_t)grow0 * BN + gcol;
#pragma unroll
      for (int reg = 0; reg < 4; ++reg) ep[(size_t)reg * BN] = pk.h[reg];
      *reinterpret_cast<uint2*>(ET + ((size_t)p << 20) + ((size_t)gcol << 10) + grow0) = pk.w;
    }
}

// ================= Sinkhorn machinery (R11 proven) ==========================
__device__ __forceinline__ float fold4(float s0, float s1, float s2, float s3,
                                       int lane) {
  float a01 = ((lane & 32) ? s1 : s0) + __shfl_xor(((lane & 32) ? s0 : s1), 32);
  float a23 = ((lane & 32) ? s3 : s2) + __shfl_xor(((lane & 32) ? s2 : s3), 32);
  float z = ((lane & 16) ? a23 : a01) + __shfl_xor(((lane & 16) ? a01 : a23), 16);
#pragma unroll
  for (int off = 8; off; off >>= 1) z += __shfl_xor(z, off);
  return z;
}

template <int NR>
__device__ __forceinline__ void load_rowsN(const __half* M, int R0, int t,
                                           uint2 (&w)[NR]) {
  const uint2* Mb = reinterpret_cast<const uint2*>(M) + ((size_t)R0 << 8);
#pragma unroll
  for (int r = 0; r < NR; ++r) w[r] = Mb[(r << 8) + t];
}

template <int NR, bool WSUM>
__device__ __forceinline__ void phase_rowsN(const uint2 (&w)[NR], float4 uv,
                                            float* red, int t) {
  const int lane = t & 63, wv = t >> 6;
#pragma unroll
  for (int g = 0; g < NR / 4; ++g) {
    float s[4];
#pragma unroll
    for (int r = 0; r < 4; ++r) {
      uint2 ww = w[g * 4 + r];
      float2 f0 = __half22float2(*reinterpret_cast<const __half2*>(&ww.x));
      float2 f1 = __half22float2(*reinterpret_cast<const __half2*>(&ww.y));
      if (WSUM) {
        s[r] = f0.x * uv.x * (1.f - 0.1f * __logf(f0.x)) +
               f0.y * uv.y * (1.f - 0.1f * __logf(f0.y)) +
               f1.x * uv.z * (1.f - 0.1f * __logf(f1.x)) +
               f1.y * uv.w * (1.f - 0.1f * __logf(f1.y));
      } else {
        s[r] = f0.x * uv.x + f0.y * uv.y + f1.x * uv.z + f1.y * uv.w;
      }
    }
    float z = fold4(s[0], s[1], s[2], s[3], lane);
    if ((lane & 15) == 0) {
      int lg = lane >> 4;
      int row = ((lg & 1) << 1) | (lg >> 1);
      red[wv * NR + g * 4 + row] = z;
    }
  }
}

// half-step, RPBH rows/block. FIRST: uin == 1 (skips load, no init dispatch).
template <bool FIRST>
__global__ __launch_bounds__(256) void fb_half(
    const __half* __restrict__ M, const float* __restrict__ uin,
    float* __restrict__ uout, int it, const int* __restrict__ nit) {
  if (it >= *nit) return;
  __shared__ float red[4 * RPBH];
  const int t = threadIdx.x, b = blockIdx.x;
  const int R0 = b * RPBH, k = R0 >> 10;
  uint2 w[RPBH];
  load_rowsN<RPBH>(M, R0, t, w);
  float4 uv;
  if (FIRST) uv = make_float4(1.f, 1.f, 1.f, 1.f);
  else uv = reinterpret_cast<const float4*>(uin + (k << 10))[t];
  phase_rowsN<RPBH, false>(w, uv, red, t);
  __syncthreads();
  if (t < RPBH) {
    float S = red[t] + red[RPBH + t] + red[2 * RPBH + t] + red[3 * RPBH + t];
    uout[R0 + t] = 1.f / (1024.f * S);
  }
}

__global__ __launch_bounds__(256) void fb_wsum(
    const __half* __restrict__ E, const float* __restrict__ uf,
    const float* __restrict__ ug, double* __restrict__ Wp) {
  __shared__ float red[4 * RPBW];
  __shared__ double red2[RPBW];
  const int t = threadIdx.x, b = blockIdx.x;
  const int R0 = b * RPBW, k = R0 >> 10;
  uint2 w[RPBW];
  load_rowsN<RPBW>(E, R0, t, w);
  phase_rowsN<RPBW, true>(w, reinterpret_cast<const float4*>(ug + (k << 10))[t], red, t);
  __syncthreads();
  if (t < RPBW)
    red2[t] = (double)(red[t] + red[RPBW + t] + red[2 * RPBW + t] + red[3 * RPBW + t]) *
              (double)uf[R0 + t];
  __syncthreads();
  if (t == 0) {
    double bp = 0.0;
#pragma unroll
    for (int r = 0; r < RPBW; ++r) bp += red2[r];
    Wp[b] = ((k < 4) ? 1.0 : -2.0) * bp;
  }
}

__global__ __launch_bounds__(256) void fb_final(
    const double* __restrict__ Wp, float* __restrict__ out) {
  __shared__ double redf[4];
  const int t = threadIdx.x;
  double p = 0.0;
  for (int i = t; i < GBLKW; i += 256) p += Wp[i];
#pragma unroll
  for (int off = 32; off; off >>= 1) p += __shfl_down(p, off);
  if ((t & 63) == 0) redf[t >> 6] = p;
  __syncthreads();
  if (t == 0) out[0] = (float)(redf[0] + redf[1] + redf[2] + redf[3]);
}

extern "C" void kernel_launch(void* const* d_in, const int* in_sizes, int n_in,
                              void* d_out, int out_size, void* d_ws, size_t ws_size,
                              hipStream_t stream) {
  (void)in_sizes; (void)n_in; (void)out_size; (void)ws_size;
  const float* x  = (const float*)d_in[0];
  const float* xp = (const float*)d_in[1];
  const float* y  = (const float*)d_in[2];
  const float* yp = (const float*)d_in[3];
  const float* Wc = (const float*)d_in[4];
  const float* bc = (const float*)d_in[5];
  const int*  nit = (const int*)d_in[6];

  char* ws = (char*)d_ws;
  const size_t MB = 1024 * 1024;
  const size_t szEh = (size_t)NK * BN * BN * 2;   // 12.58 MB
  // Pp (KS=8: 33.55 MB) occupies [0,34MB); dead after critic_norm.
  // E at 0 and ET at szEh alias it (written by cosine_mfma afterwards).
  float*  Pp  = (float*)(ws);
  __half* Eh  = (__half*)(ws);
  __half* EhT = (__half*)(ws + szEh);
  unsigned short* Fh   = (unsigned short*)(ws + 34 * MB);  // 2.10 MB
  unsigned short* Fl   = (unsigned short*)(ws + 37 * MB);  // 2.10 MB
  unsigned short* WcTh = (unsigned short*)(ws + 40 * MB);  // 1.57 MB
  unsigned short* WcTl = (unsigned short*)(ws + 42 * MB);  // 1.57 MB
  float*  uf = (float*)(ws + 44 * MB);
  float*  ug = uf + NK * BN;
  double* Wp = (double*)(ug + NK * BN);

  wct_prep<<<dim3(DIN / 64, DE / 64), 256, 0, stream>>>(Wc, WcTh, WcTl);
  critic_mfma<<<dim3(4096 / BM, DE / BNC, KS), 256, 0, stream>>>(
      x, xp, y, yp, WcTh, WcTl, Pp);
  critic_norm<<<4096, 256, 0, stream>>>(Pp, bc, Fh, Fl);
  cosine_mfma<<<dim3(BN / 128, BN / 128, NK), 256, 0, stream>>>(Fh, Fl, Eh, EhT);

  // it=0 f-step: ug == 1 implicit (no init dispatch needed)
  fb_half<true><<<GBLKH, 256, 0, stream>>>(Eh, nullptr, uf, 0, nit);
  fb_half<false><<<GBLKH, 256, 0, stream>>>(EhT, uf, ug, 0, nit);
  for (int it = 1; it < MAXIT; ++it) {
    fb_half<false><<<GBLKH, 256, 0, stream>>>(Eh, ug, uf, it, nit);
    fb_half<false><<<GBLKH, 256, 0, stream>>>(EhT, uf, ug, it, nit);
  }
  fb_wsum<<<GBLKW, 256, 0, stream>>>(Eh, uf, ug, Wp);
  fb_final<<<1, 256, 0, stream>>>(Wp, (float*)d_out);
}

// Round 14
// 205.741 us; speedup vs baseline: 1.0333x; 1.0333x over previous
//
#include <hip/hip_runtime.h>
#include <hip/hip_fp16.h>
#include <math.h>

#define BN 1024      // batch
#define DIN 3072
#define DE 256
#define NK 6
#define KS 8         // critic split-K factor (512 blocks -> 2/CU)
#define GBLKH 1536   // sinkhorn half-step blocks (6/CU)
#define RPBH 4       // rows per half-step block
#define GBLKW 384    // wsum blocks
#define RPBW 16      // rows per wsum block
#define MAXIT 20
#define BM 128       // critic block tile rows (R8/R11 proven config)
#define BNC 128
#define KSTEP 32
#define LDA 40       // LDS row stride (bf16 elems): 80 B -> 16B-aligned

constexpr float K2F = 14.4269504088896340736f;  // (1/eps)*log2(e), eps=0.1

typedef short short8 __attribute__((ext_vector_type(8)));
typedef float float4v __attribute__((ext_vector_type(4)));
typedef unsigned short ushort4v __attribute__((ext_vector_type(4)));

__device__ __forceinline__ unsigned short f2bf(float x) {  // RNE, no NaN path
  union { float f; unsigned u; } v; v.f = x;
  unsigned r = v.u + 0x7FFF + ((v.u >> 16) & 1);
  return (unsigned short)(r >> 16);
}
__device__ __forceinline__ float bf2f(unsigned short h) {
  union { float f; unsigned u; } v; v.u = ((unsigned)h) << 16;
  return v.f;
}

// ---------------- Wc -> WcT (256x3072) split into bf16 hi/lo ----------------
__global__ __launch_bounds__(256) void wct_prep(
    const float* __restrict__ Wc, unsigned short* __restrict__ WcTh,
    unsigned short* __restrict__ WcTl) {
  __shared__ float tile[64][65];
  const int t = threadIdx.x;
  const int kb = blockIdx.x * 64, cb = blockIdx.y * 64;
#pragma unroll
  for (int i = 0; i < 4; ++i) {
    int k = (t >> 4) + i * 16;
    int c = (t & 15) * 4;
    float4 v = *(const float4*)&Wc[(size_t)(kb + k) * DE + cb + c];
    tile[k][c] = v.x; tile[k][c + 1] = v.y; tile[k][c + 2] = v.z; tile[k][c + 3] = v.w;
  }
  __syncthreads();
#pragma unroll
  for (int i = 0; i < 4; ++i) {
    int c = (t >> 4) + i * 16;
    int k = (t & 15) * 4;
    ushort4v h, l;
#pragma unroll
    for (int j = 0; j < 4; ++j) {
      float v = tile[k + j][c];
      unsigned short hh = f2bf(v);
      h[j] = hh; l[j] = f2bf(v - bf2f(hh));
    }
    *(ushort4v*)&WcTh[(size_t)(cb + c) * DIN + kb + k] = h;
    *(ushort4v*)&WcTl[(size_t)(cb + c) * DIN + kb + k] = l;
  }
}

// ---------------- critic GEMM via bf16x2-split MFMA (R8/R11 proven) ---------
__global__ __launch_bounds__(256) void critic_mfma(
    const float* __restrict__ x, const float* __restrict__ xp,
    const float* __restrict__ y, const float* __restrict__ yp,
    const unsigned short* __restrict__ WcTh,
    const unsigned short* __restrict__ WcTl, float* __restrict__ Pp) {
  __shared__ unsigned short Ah[BM][LDA], Al[BM][LDA];
  __shared__ unsigned short Bh[BNC][LDA], Bl[BNC][LDA];
  const int t = threadIdx.x;
  const int rt = blockIdx.x, ct = blockIdx.y, ks = blockIdx.z;
  const int R0 = rt * BM;
  const int m = R0 >> 10, r0 = R0 & 1023;
  const float* src = (m == 0) ? x : (m == 1) ? xp : (m == 2) ? y : yp;
  const int wid = t >> 6, lane = t & 63;
  const int wy = wid >> 1, wx = wid & 1;
  const int fr = lane & 15, fg = lane >> 4;

  float4v acc[4][4];
#pragma unroll
  for (int i = 0; i < 4; ++i)
#pragma unroll
    for (int j = 0; j < 4; ++j) acc[i][j] = (float4v){0.f, 0.f, 0.f, 0.f};

  const int kbase = ks * (DIN / KS);
  for (int k0 = 0; k0 < DIN / KS; k0 += KSTEP) {
    const int kg = kbase + k0;
    __syncthreads();
    {
      int row = t >> 1, kq = (t & 1) * 16;
      const float* ap = src + (size_t)(r0 + row) * DIN + kg + kq;
      float4 a0 = *(const float4*)(ap);
      float4 a1 = *(const float4*)(ap + 4);
      float4 a2 = *(const float4*)(ap + 8);
      float4 a3 = *(const float4*)(ap + 12);
      float av[16] = {a0.x, a0.y, a0.z, a0.w, a1.x, a1.y, a1.z, a1.w,
                      a2.x, a2.y, a2.z, a2.w, a3.x, a3.y, a3.z, a3.w};
      short8 h0, h1, l0, l1;
#pragma unroll
      for (int j = 0; j < 8; ++j) {
        unsigned short h = f2bf(av[j]);
        h0[j] = (short)h; l0[j] = (short)f2bf(av[j] - bf2f(h));
        unsigned short g = f2bf(av[j + 8]);
        h1[j] = (short)g; l1[j] = (short)f2bf(av[j + 8] - bf2f(g));
      }
      *(short8*)&Ah[row][kq] = h0; *(short8*)&Ah[row][kq + 8] = h1;
      *(short8*)&Al[row][kq] = l0; *(short8*)&Al[row][kq + 8] = l1;
    }
    {
      int col = t >> 1, kq = (t & 1) * 16;
      const unsigned short* bph = WcTh + (size_t)(ct * BNC + col) * DIN + kg + kq;
      const unsigned short* bpl = WcTl + (size_t)(ct * BNC + col) * DIN + kg + kq;
      short8 h0 = *(const short8*)(bph);
      short8 h1 = *(const short8*)(bph + 8);
      short8 l0 = *(const short8*)(bpl);
      short8 l1 = *(const short8*)(bpl + 8);
      *(short8*)&Bh[col][kq] = h0; *(short8*)&Bh[col][kq + 8] = h1;
      *(short8*)&Bl[col][kq] = l0; *(short8*)&Bl[col][kq + 8] = l1;
    }
    __syncthreads();
    short8 afh[4], afl[4], bfh[4], bfl[4];
#pragma unroll
    for (int i = 0; i < 4; ++i) {
      int row = wy * 64 + i * 16 + fr;
      afh[i] = *(const short8*)&Ah[row][fg * 8];
      afl[i] = *(const short8*)&Al[row][fg * 8];
      int col = wx * 64 + i * 16 + fr;
      bfh[i] = *(const short8*)&Bh[col][fg * 8];
      bfl[i] = *(const short8*)&Bl[col][fg * 8];
    }
#pragma unroll
    for (int i = 0; i < 4; ++i)
#pragma unroll
      for (int j = 0; j < 4; ++j) {
        acc[i][j] = __builtin_amdgcn_mfma_f32_16x16x32_bf16(afh[i], bfh[j], acc[i][j], 0, 0, 0);
        acc[i][j] = __builtin_amdgcn_mfma_f32_16x16x32_bf16(afh[i], bfl[j], acc[i][j], 0, 0, 0);
        acc[i][j] = __builtin_amdgcn_mfma_f32_16x16x32_bf16(afl[i], bfh[j], acc[i][j], 0, 0, 0);
      }
  }
#pragma unroll
  for (int i = 0; i < 4; ++i)
#pragma unroll
    for (int j = 0; j < 4; ++j) {
      int grow = R0 + wy * 64 + i * 16 + fg * 4;
      int gcol = ct * BNC + wx * 64 + j * 16 + fr;
#pragma unroll
      for (int reg = 0; reg < 4; ++reg)
        Pp[((size_t)ks * 4096 + grow + reg) * DE + gcol] = acc[i][j][reg];
    }
}

// -------- combine split-K + bias + row-normalize -> F as bf16 hi/lo ---------
__global__ __launch_bounds__(256) void critic_norm(
    const float* __restrict__ Pp, const float* __restrict__ bc,
    unsigned short* __restrict__ Fh, unsigned short* __restrict__ Fl) {
  __shared__ double red[4];
  __shared__ double nrm2s;
  const int row = blockIdx.x, t = threadIdx.x;
  double val = (double)bc[t];
#pragma unroll
  for (int ks = 0; ks < KS; ++ks)
    val += (double)Pp[((size_t)ks * 4096 + row) * DE + t];
  double ss = val * val;
#pragma unroll
  for (int off = 32; off; off >>= 1) ss += __shfl_down(ss, off);
  if ((t & 63) == 0) red[t >> 6] = ss;
  __syncthreads();
  if (t == 0) nrm2s = red[0] + red[1] + red[2] + red[3];
  __syncthreads();
  float fv = (float)(val / sqrt(nrm2s));
  unsigned short h = f2bf(fv);
  Fh[(size_t)row * DE + t] = h;
  Fl[(size_t)row * DE + t] = f2bf(fv - bf2f(h));
}

// ---- 6 cosine matrices via MFMA -> Eh = exp(dot/eps) fp16, + EhT -----------
__global__ __launch_bounds__(256) void cosine_mfma(
    const unsigned short* __restrict__ Fh, const unsigned short* __restrict__ Fl,
    __half* __restrict__ E, __half* __restrict__ ET) {
  __shared__ unsigned short Ah[128][LDA], Al[128][LDA];
  __shared__ unsigned short Bh[128][LDA], Bl[128][LDA];
  const int pa[NK] = {0, 0, 1, 1, 0, 2};
  const int pb[NK] = {2, 3, 2, 3, 1, 3};
  const int p = blockIdx.z;
  const int ti = blockIdx.y, tj = blockIdx.x;
  const int t = threadIdx.x;
  const int wid = t >> 6, lane = t & 63;
  const int wy = wid >> 1, wx = wid & 1;
  const int fr = lane & 15, fg = lane >> 4;
  const size_t rbase = (size_t)(pa[p] * BN + ti * 128) * DE;
  const size_t cbase = (size_t)(pb[p] * BN + tj * 128) * DE;

  float4v acc[4][4];
#pragma unroll
  for (int i = 0; i < 4; ++i)
#pragma unroll
    for (int j = 0; j < 4; ++j) acc[i][j] = (float4v){0.f, 0.f, 0.f, 0.f};

  for (int kg = 0; kg < DE; kg += KSTEP) {
    __syncthreads();
    {
      int row = t >> 1, kq = (t & 1) * 16;
      const unsigned short* ah = Fh + rbase + (size_t)row * DE + kg + kq;
      const unsigned short* al = Fl + rbase + (size_t)row * DE + kg + kq;
      *(short8*)&Ah[row][kq] = *(const short8*)(ah);
      *(short8*)&Ah[row][kq + 8] = *(const short8*)(ah + 8);
      *(short8*)&Al[row][kq] = *(const short8*)(al);
      *(short8*)&Al[row][kq + 8] = *(const short8*)(al + 8);
      const unsigned short* bh = Fh + cbase + (size_t)row * DE + kg + kq;
      const unsigned short* bl = Fl + cbase + (size_t)row * DE + kg + kq;
      *(short8*)&Bh[row][kq] = *(const short8*)(bh);
      *(short8*)&Bh[row][kq + 8] = *(const short8*)(bh + 8);
      *(short8*)&Bl[row][kq] = *(const short8*)(bl);
      *(short8*)&Bl[row][kq + 8] = *(const short8*)(bl + 8);
    }
    __syncthreads();
    short8 afh[4], afl[4], bfh[4], bfl[4];
#pragma unroll
    for (int i = 0; i < 4; ++i) {
      int row = wy * 64 + i * 16 + fr;
      afh[i] = *(const short8*)&Ah[row][fg * 8];
      afl[i] = *(const short8*)&Al[row][fg * 8];
      int col = wx * 64 + i * 16 + fr;
      bfh[i] = *(const short8*)&Bh[col][fg * 8];
      bfl[i] = *(const short8*)&Bl[col][fg * 8];
    }
#pragma unroll
    for (int i = 0; i < 4; ++i)
#pragma unroll
      for (int j = 0; j < 4; ++j) {
        acc[i][j] = __builtin_amdgcn_mfma_f32_16x16x32_bf16(afh[i], bfh[j], acc[i][j], 0, 0, 0);
        acc[i][j] = __builtin_amdgcn_mfma_f32_16x16x32_bf16(afh[i], bfl[j], acc[i][j], 0, 0, 0);
        acc[i][j] = __builtin_amdgcn_mfma_f32_16x16x32_bf16(afl[i], bfh[j], acc[i][j], 0, 0, 0);
      }
  }
#pragma unroll
  for (int i = 0; i < 4; ++i)
#pragma unroll
    for (int j = 0; j < 4; ++j) {
      int grow0 = ti * 128 + wy * 64 + i * 16 + fg * 4;
      int gcol = tj * 128 + wx * 64 + j * 16 + fr;
      union { __half h[4]; uint2 w; } pk;
#pragma unroll
      for (int reg = 0; reg < 4; ++reg)
        pk.h[reg] = __float2half(exp2f(acc[i][j][reg] * K2F));
      __half* ep = E + ((size_t)p << 20) + (size_t)grow0 * BN + gcol;
#pragma unroll
      for (int reg = 0; reg < 4; ++reg) ep[(size_t)reg * BN] = pk.h[reg];
      *reinterpret_cast<uint2*>(ET + ((size_t)p << 20) + ((size_t)gcol << 10) + grow0) = pk.w;
    }
}

// ================= Sinkhorn machinery (R11 proven) ==========================
__device__ __forceinline__ float fold4(float s0, float s1, float s2, float s3,
                                       int lane) {
  float a01 = ((lane & 32) ? s1 : s0) + __shfl_xor(((lane & 32) ? s0 : s1), 32);
  float a23 = ((lane & 32) ? s3 : s2) + __shfl_xor(((lane & 32) ? s2 : s3), 32);
  float z = ((lane & 16) ? a23 : a01) + __shfl_xor(((lane & 16) ? a01 : a23), 16);
#pragma unroll
  for (int off = 8; off; off >>= 1) z += __shfl_xor(z, off);
  return z;
}

template <int NR>
__device__ __forceinline__ void load_rowsN(const __half* M, int R0, int t,
                                           uint2 (&w)[NR]) {
  const uint2* Mb = reinterpret_cast<const uint2*>(M) + ((size_t)R0 << 8);
#pragma unroll
  for (int r = 0; r < NR; ++r) w[r] = Mb[(r << 8) + t];
}

template <int NR, bool WSUM>
__device__ __forceinline__ void phase_rowsN(const uint2 (&w)[NR], float4 uv,
                                            float* red, int t) {
  const int lane = t & 63, wv = t >> 6;
#pragma unroll
  for (int g = 0; g < NR / 4; ++g) {
    float s[4];
#pragma unroll
    for (int r = 0; r < 4; ++r) {
      uint2 ww = w[g * 4 + r];
      float2 f0 = __half22float2(*reinterpret_cast<const __half2*>(&ww.x));
      float2 f1 = __half22float2(*reinterpret_cast<const __half2*>(&ww.y));
      if (WSUM) {
        s[r] = f0.x * uv.x * (1.f - 0.1f * __logf(f0.x)) +
               f0.y * uv.y * (1.f - 0.1f * __logf(f0.y)) +
               f1.x * uv.z * (1.f - 0.1f * __logf(f1.x)) +
               f1.y * uv.w * (1.f - 0.1f * __logf(f1.y));
      } else {
        s[r] = f0.x * uv.x + f0.y * uv.y + f1.x * uv.z + f1.y * uv.w;
      }
    }
    float z = fold4(s[0], s[1], s[2], s[3], lane);
    if ((lane & 15) == 0) {
      int lg = lane >> 4;
      int row = ((lg & 1) << 1) | (lg >> 1);
      red[wv * NR + g * 4 + row] = z;
    }
  }
}

// half-step, RPBH rows/block. FIRST: uin == 1 (skips load, no init dispatch).
template <bool FIRST>
__global__ __launch_bounds__(256) void fb_half(
    const __half* __restrict__ M, const float* __restrict__ uin,
    float* __restrict__ uout, int it, const int* __restrict__ nit) {
  if (it >= *nit) return;
  __shared__ float red[4 * RPBH];
  const int t = threadIdx.x, b = blockIdx.x;
  const int R0 = b * RPBH, k = R0 >> 10;
  uint2 w[RPBH];
  load_rowsN<RPBH>(M, R0, t, w);
  float4 uv;
  if (FIRST) uv = make_float4(1.f, 1.f, 1.f, 1.f);
  else uv = reinterpret_cast<const float4*>(uin + (k << 10))[t];
  phase_rowsN<RPBH, false>(w, uv, red, t);
  __syncthreads();
  if (t < RPBH) {
    float S = red[t] + red[RPBH + t] + red[2 * RPBH + t] + red[3 * RPBH + t];
    uout[R0 + t] = 1.f / (1024.f * S);
  }
}

__global__ __launch_bounds__(256) void fb_wsum(
    const __half* __restrict__ E, const float* __restrict__ uf,
    const float* __restrict__ ug, double* __restrict__ Wp) {
  __shared__ float red[4 * RPBW];
  __shared__ double red2[RPBW];
  const int t = threadIdx.x, b = blockIdx.x;
  const int R0 = b * RPBW, k = R0 >> 10;
  uint2 w[RPBW];
  load_rowsN<RPBW>(E, R0, t, w);
  phase_rowsN<RPBW, true>(w, reinterpret_cast<const float4*>(ug + (k << 10))[t], red, t);
  __syncthreads();
  if (t < RPBW)
    red2[t] = (double)(red[t] + red[RPBW + t] + red[2 * RPBW + t] + red[3 * RPBW + t]) *
              (double)uf[R0 + t];
  __syncthreads();
  if (t == 0) {
    double bp = 0.0;
#pragma unroll
    for (int r = 0; r < RPBW; ++r) bp += red2[r];
    Wp[b] = ((k < 4) ? 1.0 : -2.0) * bp;
  }
}

__global__ __launch_bounds__(256) void fb_final(
    const double* __restrict__ Wp, float* __restrict__ out) {
  __shared__ double redf[4];
  const int t = threadIdx.x;
  double p = 0.0;
  for (int i = t; i < GBLKW; i += 256) p += Wp[i];
#pragma unroll
  for (int off = 32; off; off >>= 1) p += __shfl_down(p, off);
  if ((t & 63) == 0) redf[t >> 6] = p;
  __syncthreads();
  if (t == 0) out[0] = (float)(redf[0] + redf[1] + redf[2] + redf[3]);
}

extern "C" void kernel_launch(void* const* d_in, const int* in_sizes, int n_in,
                              void* d_out, int out_size, void* d_ws, size_t ws_size,
                              hipStream_t stream) {
  (void)in_sizes; (void)n_in; (void)out_size; (void)ws_size;
  const float* x  = (const float*)d_in[0];
  const float* xp = (const float*)d_in[1];
  const float* y  = (const float*)d_in[2];
  const float* yp = (const float*)d_in[3];
  const float* Wc = (const float*)d_in[4];
  const float* bc = (const float*)d_in[5];
  const int*  nit = (const int*)d_in[6];

  char* ws = (char*)d_ws;
  const size_t MB = 1024 * 1024;
  const size_t szEh = (size_t)NK * BN * BN * 2;   // 12.58 MB
  // Pp (KS=8: 33.55 MB) occupies [0,34MB); dead after critic_norm.
  // E at 0 and ET at szEh alias it (written by cosine_mfma afterwards).
  float*  Pp  = (float*)(ws);
  __half* Eh  = (__half*)(ws);
  __half* EhT = (__half*)(ws + szEh);
  unsigned short* Fh   = (unsigned short*)(ws + 34 * MB);  // 2.10 MB
  unsigned short* Fl   = (unsigned short*)(ws + 37 * MB);  // 2.10 MB
  unsigned short* WcTh = (unsigned short*)(ws + 40 * MB);  // 1.57 MB
  unsigned short* WcTl = (unsigned short*)(ws + 42 * MB);  // 1.57 MB
  float*  uf = (float*)(ws + 44 * MB);
  float*  ug = uf + NK * BN;
  double* Wp = (double*)(ug + NK * BN);

  wct_prep<<<dim3(DIN / 64, DE / 64), 256, 0, stream>>>(Wc, WcTh, WcTl);
  critic_mfma<<<dim3(4096 / BM, DE / BNC, KS), 256, 0, stream>>>(
      x, xp, y, yp, WcTh, WcTl, Pp);
  critic_norm<<<4096, 256, 0, stream>>>(Pp, bc, Fh, Fl);
  cosine_mfma<<<dim3(BN / 128, BN / 128, NK), 256, 0, stream>>>(Fh, Fl, Eh, EhT);

  // it=0 f-step: ug == 1 implicit (no init dispatch needed)
  fb_half<true><<<GBLKH, 256, 0, stream>>>(Eh, nullptr, uf, 0, nit);
  fb_half<false><<<GBLKH, 256, 0, stream>>>(EhT, uf, ug, 0, nit);
  for (int it = 1; it < MAXIT; ++it) {
    fb_half<false><<<GBLKH, 256, 0, stream>>>(Eh, ug, uf, it, nit);
    fb_half<false><<<GBLKH, 256, 0, stream>>>(EhT, uf, ug, it, nit);
  }
  fb_wsum<<<GBLKW, 256, 0, stream>>>(Eh, uf, ug, Wp);
  fb_final<<<1, 256, 0, stream>>>(Wp, (float*)d_out);
}